// Round 1
// baseline (174.637 us; speedup 1.0000x reference)
//
#include <hip/hip_runtime.h>

#define B_SZ 512
#define V_SZ 1024
#define K_SZ 64
#define C_SZ 2048
#define A_SZ 128

// ---------------------------------------------------------------------------
// Kernel 1: alpha = exp(xs@Wa+ba), beta = exp(xs@Wb+bb),
//           new_kappa = prev_kappa + exp(xs@Wk+bk)
// One block handles 4 batch rows (reuses each W element 4x from register).
// Wave 0 -> alpha (k=0..63), wave 1 -> beta, wave 2 -> kappa.
// ---------------------------------------------------------------------------
__global__ __launch_bounds__(192) void gw_abk(
    const float* __restrict__ x,
    const float* __restrict__ prev_kappa,
    const float* __restrict__ Wa, const float* __restrict__ ba,
    const float* __restrict__ Wb, const float* __restrict__ bb,
    const float* __restrict__ Wk, const float* __restrict__ bk,
    float* __restrict__ ws_alpha, float* __restrict__ ws_beta,
    float* __restrict__ ws_kappa, float* __restrict__ out_kappa) {
  __shared__ float xs[4 * V_SZ];
  const int tid = threadIdx.x;
  const int b0 = blockIdx.x * 4;

  for (int i = tid; i < 4 * V_SZ; i += 192) {
    int row = i >> 10;
    int col = i & (V_SZ - 1);
    xs[i] = x[(size_t)(b0 + row) * V_SZ + col];
  }
  __syncthreads();

  const int which = tid >> 6;   // 0=alpha wave, 1=beta wave, 2=kappa wave
  const int k = tid & 63;
  const float* __restrict__ W = (which == 0) ? Wa : (which == 1) ? Wb : Wk;
  const float bias = ((which == 0) ? ba : (which == 1) ? bb : bk)[k];

  float acc0 = 0.f, acc1 = 0.f, acc2 = 0.f, acc3 = 0.f;
#pragma unroll 8
  for (int v = 0; v < V_SZ; ++v) {
    float w = W[v * K_SZ + k];          // lanes k=0..63 -> coalesced 256B
    acc0 = fmaf(xs[v],           w, acc0);
    acc1 = fmaf(xs[V_SZ + v],    w, acc1);
    acc2 = fmaf(xs[2 * V_SZ + v], w, acc2);
    acc3 = fmaf(xs[3 * V_SZ + v], w, acc3);
  }

  float e0 = expf(acc0 + bias);
  float e1 = expf(acc1 + bias);
  float e2 = expf(acc2 + bias);
  float e3 = expf(acc3 + bias);
  float e[4] = {e0, e1, e2, e3};

#pragma unroll
  for (int i = 0; i < 4; ++i) {
    int idx = (b0 + i) * K_SZ + k;
    if (which == 0) {
      ws_alpha[idx] = e[i];
    } else if (which == 1) {
      ws_beta[idx] = e[i];
    } else {
      float nk = prev_kappa[idx] + e[i];
      ws_kappa[idx] = nk;
      out_kappa[idx] = nk;
    }
  }
}

// ---------------------------------------------------------------------------
// Kernel 2: one block per batch row.
// Phase 1: phi[c] = sum_k alpha[k] * exp2(-log2e*beta[k]*(kappa[k]-c)^2)
//          -> LDS + global.
// Phase 2: window[a] = sum_c phi[c] * text[b][c][a], float4 streaming loads.
// ---------------------------------------------------------------------------
__global__ __launch_bounds__(512) void gw_phi_window(
    const float* __restrict__ text,
    const float* __restrict__ ws_alpha, const float* __restrict__ ws_beta,
    const float* __restrict__ ws_kappa,
    float* __restrict__ out_phi, float* __restrict__ out_window) {
  __shared__ float al[K_SZ];
  __shared__ float bn[K_SZ];   // -log2(e) * beta
  __shared__ float kap[K_SZ];
  __shared__ float phi_s[C_SZ];
  __shared__ float4 red[16][32];

  const int tid = threadIdx.x;
  const int b = blockIdx.x;

  if (tid < K_SZ) {
    al[tid]  = ws_alpha[b * K_SZ + tid];
    bn[tid]  = -1.4426950408889634f * ws_beta[b * K_SZ + tid];
    kap[tid] = ws_kappa[b * K_SZ + tid];
  }
  __syncthreads();

  // ---- Phase 1: phi ----
  for (int c = tid; c < C_SZ; c += 512) {
    float cf = (float)c;
    float s = 0.f;
#pragma unroll
    for (int k = 0; k < K_SZ; ++k) {
      float d = kap[k] - cf;              // LDS broadcast reads
      s += al[k] * exp2f(bn[k] * d * d);  // v_exp_f32
    }
    phi_s[c] = s;
    out_phi[(size_t)b * C_SZ + c] = s;
  }
  __syncthreads();

  // ---- Phase 2: window ----
  const float4* __restrict__ t4 =
      (const float4*)(text + (size_t)b * C_SZ * A_SZ);
  const int a4 = tid & 31;   // float4 column (covers A=128)
  const int cr = tid >> 5;   // 16 parallel c-rows

  float4 acc = make_float4(0.f, 0.f, 0.f, 0.f);
#pragma unroll 4
  for (int cc = cr; cc < C_SZ; cc += 16) {
    float p = phi_s[cc];
    float4 t = t4[cc * 32 + a4];          // coalesced 512B per row
    acc.x = fmaf(p, t.x, acc.x);
    acc.y = fmaf(p, t.y, acc.y);
    acc.z = fmaf(p, t.z, acc.z);
    acc.w = fmaf(p, t.w, acc.w);
  }

  red[cr][a4] = acc;
  __syncthreads();

  if (tid < 32) {
    float4 w = red[0][tid];
#pragma unroll
    for (int i = 1; i < 16; ++i) {
      float4 r = red[i][tid];
      w.x += r.x; w.y += r.y; w.z += r.z; w.w += r.w;
    }
    ((float4*)(out_window + (size_t)b * A_SZ))[tid] = w;
  }
}

extern "C" void kernel_launch(void* const* d_in, const int* in_sizes, int n_in,
                              void* d_out, int out_size, void* d_ws, size_t ws_size,
                              hipStream_t stream) {
  const float* x    = (const float*)d_in[0];
  const float* text = (const float*)d_in[1];
  const float* pk   = (const float*)d_in[2];
  const float* Wa   = (const float*)d_in[3];
  const float* ba   = (const float*)d_in[4];
  const float* Wb   = (const float*)d_in[5];
  const float* bb   = (const float*)d_in[6];
  const float* Wk   = (const float*)d_in[7];
  const float* bk   = (const float*)d_in[8];

  float* out        = (float*)d_out;
  float* out_phi    = out;                              // B*C
  float* out_kappa  = out + (size_t)B_SZ * C_SZ;        // B*K
  float* out_win    = out_kappa + (size_t)B_SZ * K_SZ;  // B*A

  float* ws         = (float*)d_ws;
  float* ws_alpha   = ws;
  float* ws_beta    = ws + (size_t)B_SZ * K_SZ;
  float* ws_kappa   = ws + (size_t)2 * B_SZ * K_SZ;

  gw_abk<<<B_SZ / 4, 192, 0, stream>>>(x, pk, Wa, ba, Wb, bb, Wk, bk,
                                       ws_alpha, ws_beta, ws_kappa, out_kappa);
  gw_phi_window<<<B_SZ, 512, 0, stream>>>(text, ws_alpha, ws_beta, ws_kappa,
                                          out_phi, out_win);
}